// Round 17
// baseline (2915.665 us; speedup 1.0000x reference)
//
#include <hip/hip_runtime.h>
#include <hip/hip_bf16.h>
#include <math.h>
#include <stdint.h>

// Problem constants
#define CCH   192      // channels
#define HWD   224      // H = W = 224
#define NWIN  8192     // 8 * 32 * 32 windows
#define NPIX  49       // 7*7 pixels per window
#define KDIM  192      // GEMM1 K
#define NHEAD 6
#define ROWB  (KDIM * 2)   // 384 bytes per LDS row
#define MULQ  0.2550348616845977f   // 32^-0.5 * log2(e), folded into W_q/b_q

typedef __bf16 bf16x8 __attribute__((ext_vector_type(8)));
typedef __bf16 bf16x2 __attribute__((ext_vector_type(2)));
typedef float  f32x4  __attribute__((ext_vector_type(4)));

// Convert W (384x192 f32) to bf16 pre-swizzled into MFMA B-fragment order,
// with scale*log2e pre-folded into the q half (rows 0..191).
// out[((ng*6 + kk)*4 + lg)*128 + lr*8 + e] = W[(ng*16+lr)*192 + kk*32+lg*8+e]
// Also writes the (scaled) bias as f32 at wbf+73728.
__global__ void wconv_kernel(const float* __restrict__ w,
                             const float* __restrict__ bq,
                             uint16_t* __restrict__ wbf) {
    int o = blockIdx.x * 256 + threadIdx.x;
    if (o >= 384 * 192) return;
    if (o < 384) {
        float bb = bq[o];
        if (o < 192) bb *= MULQ;
        ((float*)(wbf + 384 * 192))[o] = bb;
    }
    int e  = o & 7;
    int t  = o >> 3;
    int lr = t & 15;  t >>= 4;
    int lg = t & 3;   t >>= 2;
    int kk = t % 6;
    int ng = t / 6;
    int col  = ng * 16 + lr;
    int kcol = kk * 32 + lg * 8 + e;
    float wv = w[col * KDIM + kcol];
    if (col < 192) wv *= MULQ;            // q half pre-scaled
    __bf16 v = (__bf16)wv;
    wbf[o] = __builtin_bit_cast(uint16_t, v);
}

// 256 persistent blocks (1/CU), 1024 threads = 16 waves. Block owns window
// row (b, wh), loops its 32 windows. __launch_bounds__(1024,4): 128-reg
// budget, so g[12] prefetch survives across barriers WITHOUT spilling
// (the (1024,8)/64-reg budget spilled on any cross-barrier live value —
// R5/R6/R9/R13/R15). Occupancy drops to 16 waves/CU, which R4==R10 showed
// costs almost nothing. Separate X/Q/K buffers (56448 B) let phase 3 write
// Q/K while GEMM1's X-reads need no barrier -> 2 barriers/window (was 3).
// g[12] for window j+1 issues right after B2, drains at the X-write after
// phase 4 -> gather latency covered by GEMM2+softmax+stores.
__global__ __launch_bounds__(1024, 4)
void attn_win_kernel(const float* __restrict__ x,
                     const uint16_t* __restrict__ wbf,
                     float* __restrict__ out) {
    __shared__ uint16_t ldsX[NPIX * KDIM];   // xw tile of current window
    __shared__ uint16_t ldsQ[NPIX * KDIM];   // q
    __shared__ uint16_t ldsK[NPIX * KDIM];   // k

    const int tid  = threadIdx.x;
    const int wave = tid >> 6;   // 0..15
    const int l    = tid & 63;
    const int lg   = l >> 4;     // 0..3
    const int lr   = l & 15;     // 0..15

    // block -> (image, window-row). XCD i streams image i (256 = 8 * 32).
    const int b   = (int)blockIdx.x & 7;
    const int wh  = (int)blockIdx.x >> 3;    // 0..31
    const int h0  = wh * 7;

    // GEMM1 wave roles
    const int mp = wave & 1;
    const int cg = wave >> 1;    // 0..7
    const float* biasp = (const float*)(wbf + 384 * 192);
    float bias0[3];
    #pragma unroll
    for (int nt = 0; nt < 3; ++nt)
        bias0[nt] = biasp[cg * 48 + nt * 16 + lr];

    // gather geometry: lane = pixel (49 active), wave owns 12 channels
    const int pr = (l * 37) >> 8;            // l / 7 for l in [0,49)
    const int ps = l - pr * 7;
    const float* xlane = x + (size_t)(b * CCH + wave * 12) * (HWD * HWD)
                           + (size_t)(h0 + pr) * HWD + ps;   // +c*HW2 +ww*7
    const uint32_t rb  = (uint32_t)(l * ROWB + wave * 24);
    const uint32_t swz = (uint32_t)((l & 7) << 4);
    const bool glane = (l < NPIX);

    // phase-4 constants
    const int qt    = wave & 3;
    const int qrow  = qt * 16 + lr;
    const int qrc   = qrow > 48 ? 48 : qrow;
    const uint32_t qswz = (uint32_t)((qrc & 7) << 4);
    const int h1 = wave >> 2;                // first head (0..3)

    // ---- Prologue: gather + write window 0 -> ldsX (one exposed latency)
    float g[12];
    if (glane) {
        #pragma unroll
        for (int c = 0; c < 12; ++c)
            g[c] = xlane[(size_t)c * (HWD * HWD)];
        #pragma unroll
        for (int c = 0; c < 12; c += 2) {
            bf16x2 p = { (__bf16)g[c], (__bf16)g[c + 1] };
            *(uint32_t*)((char*)ldsX + ((rb + (uint32_t)(c * 2)) ^ swz)) =
                __builtin_bit_cast(uint32_t, p);
        }
    }
    __syncthreads();   // X(0) ready

    for (int j = 0; j < 32; ++j) {
        const bool pf = (j < 31) && glane;

        // ---- Phase 2: GEMM1 from ldsX + wbf (+bias via acc init)
        f32x4 acc[2][3];
        #pragma unroll
        for (int nt = 0; nt < 3; ++nt) {
            float bb = bias0[nt];
            #pragma unroll
            for (int mt = 0; mt < 2; ++mt)
                acc[mt][nt] = f32x4{bb, bb, bb, bb};
        }
        #pragma unroll
        for (int kk = 0; kk < 6; ++kk) {
            bf16x8 afr[2];
            #pragma unroll
            for (int mt = 0; mt < 2; ++mt) {
                int row = mp * 32 + mt * 16 + lr;
                if (row > 48) row = 48;               // clamp: no pad rows
                int byte = (row * ROWB + kk * 64 + lg * 16) ^ ((row & 7) << 4);
                afr[mt] = *(const bf16x8*)((const char*)ldsX + byte);
            }
            bf16x8 bfr[3];
            #pragma unroll
            for (int nt = 0; nt < 3; ++nt)
                bfr[nt] = *(const bf16x8*)(
                    wbf + (((cg * 3 + nt) * 6 + kk) * 4 + lg) * 128 + lr * 8);
            #pragma unroll
            for (int nt = 0; nt < 3; ++nt)
                #pragma unroll
                for (int mt = 0; mt < 2; ++mt)
                    acc[mt][nt] = __builtin_amdgcn_mfma_f32_16x16x32_bf16(
                        afr[mt], bfr[nt], acc[mt][nt], 0, 0, 0);
        }
        // no barrier: phase 3 writes Q/K, not X

        // ---- Phase 3: q -> ldsQ, k -> ldsK
        {
            const bool isq = (cg < 4);
            uint16_t* dst = isq ? ldsQ : ldsK;
            #pragma unroll
            for (int nt = 0; nt < 3; ++nt) {
                int colW = cg * 48 + nt * 16 + lr;
                int jj = isq ? colW : (colW - 192);
                #pragma unroll
                for (int mt = 0; mt < 2; ++mt) {
                    #pragma unroll
                    for (int r = 0; r < 4; ++r) {
                        int row = mp * 32 + mt * 16 + lg * 4 + r;
                        if (row < NPIX) {
                            __bf16 bv = (__bf16)acc[mt][nt][r];
                            *(__bf16*)((char*)dst +
                                ((row * ROWB + jj * 2) ^ ((row & 7) << 4))) = bv;
                        }
                    }
                }
            }
        }
        __syncthreads();   // B2: Q/K visible to all waves

        // ---- issue prefetch for window j+1 (drains at X-write below,
        // covered by phase 4's MFMA + softmax + stores)
        if (pf) {
            const float* xpn = xlane + (size_t)((j + 1) * 7);
            #pragma unroll
            for (int c = 0; c < 12; ++c)
                g[c] = xpn[(size_t)c * (HWD * HWD)];
        }

        // ---- Phase 4: swapped-operand GEMM2 + lane-local softmax + stores
        float* outw = out + (size_t)((b * 32 + wh) * 32 + j) * (NHEAD * NPIX * NPIX);

        auto do_head = [&](int h) {
            const bf16x8 qfr = *(const bf16x8*)((const char*)ldsQ +
                (((uint32_t)(qrc * ROWB + h * 64 + lg * 16)) ^ qswz));

            float v[16];
            #pragma unroll
            for (int nt2 = 0; nt2 < 4; ++nt2) {
                int krow = nt2 * 16 + lr;
                if (krow > 48) krow = 48;             // clamp (masked later)
                const bf16x8 kfr = *(const bf16x8*)((const char*)ldsK +
                    (((uint32_t)(krow * ROWB + h * 64 + lg * 16)) ^ ((krow & 7) << 4)));
                f32x4 p = __builtin_amdgcn_mfma_f32_16x16x32_bf16(
                    kfr, qfr, f32x4{0.f, 0.f, 0.f, 0.f}, 0, 0, 0);
                #pragma unroll
                for (int r = 0; r < 4; ++r) {
                    int k = nt2 * 16 + lg * 4 + r;
                    v[nt2 * 4 + r] = (k < NPIX) ? p[r] : -INFINITY;
                }
            }

            float m = v[0];
            #pragma unroll
            for (int i = 1; i < 16; ++i) m = fmaxf(m, v[i]);
            m = fmaxf(m, __shfl_xor(m, 16, 64));
            m = fmaxf(m, __shfl_xor(m, 32, 64));

            float sum = 0.f;
            #pragma unroll
            for (int i = 0; i < 16; ++i) {
                v[i] = exp2f(v[i] - m);    // logits already in log2 domain
                sum += v[i];
            }
            sum += __shfl_xor(sum, 16, 64);
            sum += __shfl_xor(sum, 32, 64);
            const float inv = __fdividef(1.0f, sum);

            if (qrow < NPIX) {
                float* orow = outw + h * (NPIX * NPIX) + qrow * NPIX;
                #pragma unroll
                for (int nt2 = 0; nt2 < 3; ++nt2)
                    #pragma unroll
                    for (int r = 0; r < 4; ++r)
                        orow[nt2 * 16 + lg * 4 + r] = v[nt2 * 4 + r] * inv;
                if (lg == 0) orow[48] = v[12] * inv;
            }
        };

        do_head(h1);
        if (wave < 8) do_head(h1 + 4);   // heads 4,5

        // ---- write prefetched g -> ldsX(j+1) (vmcnt wait lands here)
        if (pf) {
            #pragma unroll
            for (int c = 0; c < 12; c += 2) {
                bf16x2 p = { (__bf16)g[c], (__bf16)g[c + 1] };
                *(uint32_t*)((char*)ldsX + ((rb + (uint32_t)(c * 2)) ^ swz)) =
                    __builtin_bit_cast(uint32_t, p);
            }
        }
        __syncthreads();   // B3: Q/K reads done + X(j+1) complete
    }
}

extern "C" void kernel_launch(void* const* d_in, const int* in_sizes, int n_in,
                              void* d_out, int out_size, void* d_ws, size_t ws_size,
                              hipStream_t stream) {
    const float* x  = (const float*)d_in[0];
    const float* W  = (const float*)d_in[1];
    const float* bq = (const float*)d_in[2];
    float* out = (float*)d_out;
    uint16_t* wbf = (uint16_t*)d_ws;   // 147456 B swizzled W + 1536 B bias f32

    wconv_kernel<<<(384 * 192 + 255) / 256, 256, 0, stream>>>(W, bq, wbf);
    attn_win_kernel<<<256, 1024, 0, stream>>>(x, wbf, out);
}

// Round 18
// 695.095 us; speedup vs baseline: 4.1946x; 4.1946x over previous
//
#include <hip/hip_runtime.h>
#include <hip/hip_bf16.h>
#include <math.h>
#include <stdint.h>

// Problem constants
#define CCH   192      // channels
#define HWD   224      // H = W = 224
#define NPIX  49       // 7*7 pixels per window
#define KDIM  192      // GEMM1 K
#define NHEAD 6
#define ROWB  (KDIM * 2)             // 384 bytes per Q/K LDS row
#define XSTR  65                     // padded f32 X row stride (2-way banks = free)
#define XBYTES (CCH * XSTR * 4)      // 49920
#define QOFF  XBYTES                 // Q region: 18816 B
#define KOFF  (XBYTES + NPIX * KDIM * 2)
#define LDSSZ (XBYTES + 2 * NPIX * KDIM * 2)   // 87552 B dynamic LDS
#define MULQ  0.2550348616845977f    // 32^-0.5 * log2(e), folded into W_q/b_q

typedef __bf16 bf16x8 __attribute__((ext_vector_type(8)));
typedef float  f32x4  __attribute__((ext_vector_type(4)));

// Async global->LDS DMA, 4 B/lane. Zero registers: data lives in the vmcnt
// queue + LDS; __syncthreads' implicit vmcnt(0) is the drain point.
__device__ __forceinline__ void gload_lds4(const float* g, float* l) {
    __builtin_amdgcn_global_load_lds(
        (const __attribute__((address_space(1))) void*)g,
        (__attribute__((address_space(3))) void*)l, 4, 0, 0);
}

// Convert W (384x192 f32) to bf16 pre-swizzled into MFMA B-fragment order,
// with scale*log2e pre-folded into the q half. Bias (scaled) at wbf+73728.
__global__ void wconv_kernel(const float* __restrict__ w,
                             const float* __restrict__ bq,
                             uint16_t* __restrict__ wbf) {
    int o = blockIdx.x * 256 + threadIdx.x;
    if (o >= 384 * 192) return;
    if (o < 384) {
        float bb = bq[o];
        if (o < 192) bb *= MULQ;
        ((float*)(wbf + 384 * 192))[o] = bb;
    }
    int e  = o & 7;
    int t  = o >> 3;
    int lr = t & 15;  t >>= 4;
    int lg = t & 3;   t >>= 2;
    int kk = t % 6;
    int ng = t / 6;
    int col  = ng * 16 + lr;
    int kcol = kk * 32 + lg * 8 + e;
    float wv = w[col * KDIM + kcol];
    if (col < 192) wv *= MULQ;            // q half pre-scaled
    __bf16 v = (__bf16)wv;
    wbf[o] = __builtin_bit_cast(uint16_t, v);
}

// 256 persistent blocks (1/CU), 1024 threads = 16 waves, block owns window
// row (b, wh) and loops its 32 windows. Allocator fact (R5-R17): the unified
// reg file splits ~evenly VGPR/AGPR, so arch cap = budget/2. (1024,4) ->
// arch cap 64; this kernel's arch live set ~55 (no cross-barrier registers:
// the x prefetch for window j+1 goes via global_load_lds DMA into an f32 LDS
// buffer, issued after B2, drained by B3's implicit vmcnt(0) — covered by
// phase 4). X stored f32 [192][65] (pad -> 2-way banks, free); phase 2
// converts to bf16 fragments in-register ((__bf16) casts -> cvt_pk).
// 2 barriers/window. Dynamic LDS 87552 B -> 1 block/CU (16 waves; R4==R10
// showed occupancy beyond this level is not the lever).
__global__ __launch_bounds__(1024, 4)
void attn_row_kernel(const float* __restrict__ x,
                     const uint16_t* __restrict__ wbf,
                     float* __restrict__ out) {
    extern __shared__ char smem[];
    float*    ldsXf = (float*)smem;                 // [192][65] f32
    uint16_t* ldsQ  = (uint16_t*)(smem + QOFF);     // q, swizzled bf16
    uint16_t* ldsK  = (uint16_t*)(smem + KOFF);     // k, swizzled bf16

    const int tid  = threadIdx.x;
    const int wave = tid >> 6;   // 0..15
    const int l    = tid & 63;
    const int lg   = l >> 4;     // 0..3
    const int lr   = l & 15;     // 0..15

    // block -> (image, window-row). Image b pinned to XCD b (256 = 8 * 32).
    const int b   = (int)blockIdx.x & 7;
    const int wh  = (int)blockIdx.x >> 3;    // 0..31
    const int h0  = wh * 7;

    // GEMM1 wave roles
    const int mp = wave & 1;
    const int cg = wave >> 1;    // 0..7
    const float* biasp = (const float*)(wbf + 384 * 192);
    float bias0[3];
    #pragma unroll
    for (int nt = 0; nt < 3; ++nt)
        bias0[nt] = biasp[cg * 48 + nt * 16 + lr];

    // gather geometry: lane = pixel (49 active), wave owns 12 channels
    const int pr = (l * 37) >> 8;            // l / 7 for l in [0,49)
    const int ps = l - pr * 7;
    const size_t HW2 = (size_t)HWD * HWD;
    const float* xlane = x + (size_t)(b * CCH + wave * 12) * HW2
                           + (size_t)(h0 + pr) * HWD + ps;   // +c*HW2 +j*7
    float* ldsXw = ldsXf + (wave * 12) * XSTR;   // wave-uniform DMA dest base
    const bool glane = (l < NPIX);

    // phase-4 constants
    const int qt    = wave & 3;
    const int qrow  = qt * 16 + lr;
    const int qrc   = qrow > 48 ? 48 : qrow;
    const uint32_t qswz = (uint32_t)((qrc & 7) << 4);
    const int h1 = wave >> 2;                // first head (0..3)

    // ---- Prologue: DMA window 0 -> ldsXf (lanes 49-63 masked; their slots
    // are never read — all fragment rows clamp to <= 48)
    if (glane) {
        #pragma unroll
        for (int c = 0; c < 12; ++c)
            gload_lds4(xlane + (size_t)c * HW2, ldsXw + c * XSTR);
    }
    __syncthreads();   // drains DMA: X(0) ready

    for (int j = 0; j < 32; ++j) {
        // ---- Phase 2: GEMM1 from f32 LDS (+bias via acc init)
        f32x4 acc[2][3];
        #pragma unroll
        for (int nt = 0; nt < 3; ++nt) {
            float bb = bias0[nt];
            #pragma unroll
            for (int mt = 0; mt < 2; ++mt)
                acc[mt][nt] = f32x4{bb, bb, bb, bb};
        }
        #pragma unroll
        for (int kk = 0; kk < 6; ++kk) {
            bf16x8 afr[2];
            #pragma unroll
            for (int mt = 0; mt < 2; ++mt) {
                int row = mp * 32 + mt * 16 + lr;
                if (row > 48) row = 48;               // clamp: no pad rows
                const float* xr = ldsXf + (kk * 32 + lg * 8) * XSTR + row;
                bf16x8 a;
                #pragma unroll
                for (int e = 0; e < 8; ++e)
                    a[e] = (__bf16)xr[e * XSTR];      // cvt_pk pairs
                afr[mt] = a;
            }
            bf16x8 bfr[3];
            #pragma unroll
            for (int nt = 0; nt < 3; ++nt)
                bfr[nt] = *(const bf16x8*)(
                    wbf + (((cg * 3 + nt) * 6 + kk) * 4 + lg) * 128 + lr * 8);
            #pragma unroll
            for (int nt = 0; nt < 3; ++nt)
                #pragma unroll
                for (int mt = 0; mt < 2; ++mt)
                    acc[mt][nt] = __builtin_amdgcn_mfma_f32_16x16x32_bf16(
                        afr[mt], bfr[nt], acc[mt][nt], 0, 0, 0);
        }
        // no barrier: phase 3 writes Q/K regions, X reads unaffected

        // ---- Phase 3: q -> ldsQ, k -> ldsK (bias/scale already in acc)
        {
            const bool isq = (cg < 4);
            uint16_t* dst = isq ? ldsQ : ldsK;
            #pragma unroll
            for (int nt = 0; nt < 3; ++nt) {
                int colW = cg * 48 + nt * 16 + lr;
                int jj = isq ? colW : (colW - 192);
                #pragma unroll
                for (int mt = 0; mt < 2; ++mt) {
                    #pragma unroll
                    for (int r = 0; r < 4; ++r) {
                        int row = mp * 32 + mt * 16 + lg * 4 + r;
                        if (row < NPIX) {
                            __bf16 bv = (__bf16)acc[mt][nt][r];
                            *(__bf16*)((char*)dst +
                                ((row * ROWB + jj * 2) ^ ((row & 7) << 4))) = bv;
                        }
                    }
                }
            }
        }
        __syncthreads();   // B2: Q/K visible AND all X(j) reads complete

        // ---- DMA prefetch window j+1 -> ldsXf (zero registers; drains at B3,
        // fully covered by phase 4's MFMA + softmax + stores)
        if (j < 31 && glane) {
            const float* gp = xlane + (size_t)((j + 1) * 7);
            #pragma unroll
            for (int c = 0; c < 12; ++c)
                gload_lds4(gp + (size_t)c * HW2, ldsXw + c * XSTR);
        }

        // ---- Phase 4: swapped-operand GEMM2 + lane-local softmax + stores
        float* outw = out + (size_t)((b * 32 + wh) * 32 + j) * (NHEAD * NPIX * NPIX);

        auto do_head = [&](int h) {
            const bf16x8 qfr = *(const bf16x8*)((const char*)ldsQ +
                (((uint32_t)(qrc * ROWB + h * 64 + lg * 16)) ^ qswz));

            float v[16];
            #pragma unroll
            for (int nt2 = 0; nt2 < 4; ++nt2) {
                int krow = nt2 * 16 + lr;
                if (krow > 48) krow = 48;             // clamp (masked later)
                const bf16x8 kfr = *(const bf16x8*)((const char*)ldsK +
                    (((uint32_t)(krow * ROWB + h * 64 + lg * 16)) ^ ((krow & 7) << 4)));
                f32x4 p = __builtin_amdgcn_mfma_f32_16x16x32_bf16(
                    kfr, qfr, f32x4{0.f, 0.f, 0.f, 0.f}, 0, 0, 0);
                #pragma unroll
                for (int r = 0; r < 4; ++r) {
                    int k = nt2 * 16 + lg * 4 + r;
                    v[nt2 * 4 + r] = (k < NPIX) ? p[r] : -INFINITY;
                }
            }

            float m = v[0];
            #pragma unroll
            for (int i = 1; i < 16; ++i) m = fmaxf(m, v[i]);
            m = fmaxf(m, __shfl_xor(m, 16, 64));
            m = fmaxf(m, __shfl_xor(m, 32, 64));

            float sum = 0.f;
            #pragma unroll
            for (int i = 0; i < 16; ++i) {
                v[i] = exp2f(v[i] - m);    // logits already in log2 domain
                sum += v[i];
            }
            sum += __shfl_xor(sum, 16, 64);
            sum += __shfl_xor(sum, 32, 64);
            const float inv = __fdividef(1.0f, sum);

            if (qrow < NPIX) {
                float* orow = outw + h * (NPIX * NPIX) + qrow * NPIX;
                #pragma unroll
                for (int nt2 = 0; nt2 < 3; ++nt2)
                    #pragma unroll
                    for (int r = 0; r < 4; ++r)
                        orow[nt2 * 16 + lg * 4 + r] = v[nt2 * 4 + r] * inv;
                if (lg == 0) orow[48] = v[12] * inv;
            }
        };

        do_head(h1);
        if (wave < 8) do_head(h1 + 4);   // heads 4,5

        __syncthreads();   // B3: DMA drained (X(j+1) ready) + Q/K reads done
    }
}

extern "C" void kernel_launch(void* const* d_in, const int* in_sizes, int n_in,
                              void* d_out, int out_size, void* d_ws, size_t ws_size,
                              hipStream_t stream) {
    const float* x  = (const float*)d_in[0];
    const float* W  = (const float*)d_in[1];
    const float* bq = (const float*)d_in[2];
    float* out = (float*)d_out;
    uint16_t* wbf = (uint16_t*)d_ws;   // 147456 B swizzled W + 1536 B bias f32

    wconv_kernel<<<(384 * 192 + 255) / 256, 256, 0, stream>>>(W, bq, wbf);
    attn_row_kernel<<<256, 1024, LDSSZ, stream>>>(x, wbf, out);
}

// Round 19
// 603.938 us; speedup vs baseline: 4.8278x; 1.1509x over previous
//
#include <hip/hip_runtime.h>
#include <hip/hip_bf16.h>
#include <math.h>
#include <stdint.h>

// Problem constants
#define CCH   192      // channels
#define HWD   224      // H = W = 224
#define NWIN  8192     // 8 * 32 * 32 windows
#define NPIX  49       // 7*7 pixels per window
#define KDIM  192      // GEMM1 K
#define NHEAD 6
#define ROWB  (KDIM * 2)             // 384 bytes per LDS row
#define NW    4                      // windows per block
#define NBLK  (NWIN / NW)            // 2048 blocks
#define XROWS (NW * NPIX)            // 196 staged pixel-rows
#define XB    (XROWS * KDIM * 2)     // 75264 B
#define QOFF  XB
#define KOFF  (XB + NPIX * KDIM * 2)
#define LDSSZ (XB + 2 * NPIX * KDIM * 2)   // 112896 B dynamic LDS
#define MULQ  0.2550348616845977f    // 32^-0.5 * log2(e), folded into W_q/b_q

typedef __bf16 bf16x8 __attribute__((ext_vector_type(8)));
typedef __bf16 bf16x2 __attribute__((ext_vector_type(2)));
typedef float  f32x4  __attribute__((ext_vector_type(4)));

// Convert W (384x192 f32) to bf16 pre-swizzled into MFMA B-fragment order,
// with scale*log2e pre-folded into the q half. Bias (scaled) at wbf+73728.
__global__ void wconv_kernel(const float* __restrict__ w,
                             const float* __restrict__ bq,
                             uint16_t* __restrict__ wbf) {
    int o = blockIdx.x * 256 + threadIdx.x;
    if (o >= 384 * 192) return;
    if (o < 384) {
        float bb = bq[o];
        if (o < 192) bb *= MULQ;
        ((float*)(wbf + 384 * 192))[o] = bb;
    }
    int e  = o & 7;
    int t  = o >> 3;
    int lr = t & 15;  t >>= 4;
    int lg = t & 3;   t >>= 2;
    int kk = t % 6;
    int ng = t / 6;
    int col  = ng * 16 + lr;
    int kcol = kk * 32 + lg * 8 + e;
    float wv = w[col * KDIM + kcol];
    if (col < 192) wv *= MULQ;            // q half pre-scaled
    __bf16 v = (__bf16)wv;
    wbf[o] = __builtin_bit_cast(uint16_t, v);
}

// 4 windows per block (2048 blocks), 1024 threads = 16 waves.
// One prologue gather stages all 4 windows' x into ldsX (196 rows bf16,
// XOR-swizzled): gather latency exposed once per 4 windows (was 4x), all 64
// lanes active (was 49), 28-contiguous-float row-runs (was 7) for proper
// coalescing. No cross-barrier register lifetime -> no spill at the measured
// 64-arch-reg cap of (1024,4) (R17's spill was g[12]+v[16] live together;
// here the gather is prologue-local). Per-window phases identical to R16.
// Dynamic LDS 112896 B -> 1 block/CU, 16 waves (R4==R10: occupancy-neutral).
// 1 + 2*NW barriers per block iteration (was 3*NW).
__global__ __launch_bounds__(1024, 4)
void attn_win_kernel(const float* __restrict__ x,
                     const uint16_t* __restrict__ wbf,
                     float* __restrict__ out) {
    extern __shared__ char smem[];
    uint16_t* ldsX = (uint16_t*)smem;               // 4 windows' xw (bf16)
    uint16_t* ldsQ = (uint16_t*)(smem + QOFF);      // q of current window
    uint16_t* ldsK = (uint16_t*)(smem + KOFF);      // k of current window

    const int tid  = threadIdx.x;
    const int wave = tid >> 6;   // 0..15
    const int l    = tid & 63;
    const int lg   = l >> 4;     // 0..3
    const int lr   = l & 15;     // 0..15

    // XCD-bijective remap (2048 % 8 == 0): XCD i streams image i.
    const int blk  = (int)blockIdx.x;
    const int blk2 = (blk & 7) * (NBLK / 8) + (blk >> 3);
    const int wbase = blk2 * NW;             // 4 consecutive windows, same row
    const int b    = wbase >> 10;
    const int wh   = (wbase >> 5) & 31;
    const int ww0  = wbase & 31;             // in {0,4,...,28}
    const int h0   = wh * 7;

    const float* biasp = (const float*)(wbf + 384 * 192);
    const int mp = wave & 1;
    const int cg = wave >> 1;    // 0..7
    float bias0[3];
    #pragma unroll
    for (int nt = 0; nt < 3; ++nt)
        bias0[nt] = biasp[cg * 48 + nt * 16 + lr];

    // phase-4 constants
    const int qt    = wave & 3;
    const int qrow  = qt * 16 + lr;
    const int qrc   = qrow > 48 ? 48 : qrow;
    const int h1 = wave >> 2;                // first head (0..3)

    const size_t HW2 = (size_t)HWD * HWD;

    // ---- Prologue: gather 4 windows -> ldsX.
    // Pixel strip: 7 rows x 28 cols (4 windows side by side). Lane covers
    // pixels p = i*64+l (i=0..3, p<196); wave owns channels wave*12..+11.
    {
        const int cbase = wave * 12;
        const float* xw = x + ((size_t)(b * CCH + cbase)) * HW2
                            + (size_t)h0 * HWD + (size_t)(ww0 * 7);
        #pragma unroll
        for (int i = 0; i < 4; ++i) {
            int p = i * 64 + l;
            if (p < XROWS) {
                int prr = (p * 586) >> 14;        // p / 28 for p < 256
                int pcc = p - prr * 28;           // 0..27
                int w   = (pcc * 37) >> 8;        // pcc / 7
                int s   = pcc - w * 7;
                int row = w * NPIX + prr * 7 + s; // LDS pixel-row (0..195)
                const float* gp = xw + (size_t)prr * HWD + pcc;
                const uint32_t rb = (uint32_t)(row * ROWB + cbase * 2);
                const uint32_t sw = (uint32_t)((row & 7) << 4);
                #pragma unroll
                for (int cp = 0; cp < 6; ++cp) {
                    float v0 = gp[(size_t)(2 * cp) * HW2];
                    float v1 = gp[(size_t)(2 * cp + 1) * HW2];
                    bf16x2 pk = { (__bf16)v0, (__bf16)v1 };
                    *(uint32_t*)((char*)ldsX + ((rb + (uint32_t)(cp * 4)) ^ sw)) =
                        __builtin_bit_cast(uint32_t, pk);
                }
            }
        }
    }
    __syncthreads();   // X of all 4 windows ready

    for (int j = 0; j < NW; ++j) {
        const int rbase = j * NPIX;

        // ---- Phase 2: GEMM1 from ldsX (+bias via acc init)
        f32x4 acc[2][3];
        #pragma unroll
        for (int nt = 0; nt < 3; ++nt) {
            float bb = bias0[nt];
            #pragma unroll
            for (int mt = 0; mt < 2; ++mt)
                acc[mt][nt] = f32x4{bb, bb, bb, bb};
        }
        #pragma unroll
        for (int kk = 0; kk < 6; ++kk) {
            bf16x8 afr[2];
            #pragma unroll
            for (int mt = 0; mt < 2; ++mt) {
                int rw = mp * 32 + mt * 16 + lr;
                if (rw > 48) rw = 48;                 // clamp within window
                int row = rbase + rw;
                int byte = (row * ROWB + kk * 64 + lg * 16) ^ ((row & 7) << 4);
                afr[mt] = *(const bf16x8*)((const char*)ldsX + byte);
            }
            bf16x8 bfr[3];
            #pragma unroll
            for (int nt = 0; nt < 3; ++nt)
                bfr[nt] = *(const bf16x8*)(
                    wbf + (((cg * 3 + nt) * 6 + kk) * 4 + lg) * 128 + lr * 8);
            #pragma unroll
            for (int nt = 0; nt < 3; ++nt)
                #pragma unroll
                for (int mt = 0; mt < 2; ++mt)
                    acc[mt][nt] = __builtin_amdgcn_mfma_f32_16x16x32_bf16(
                        afr[mt], bfr[nt], acc[mt][nt], 0, 0, 0);
        }
        // no barrier: phase 3 writes Q/K, X is read-only

        // ---- Phase 3: q -> ldsQ, k -> ldsK (bias/scale already in acc)
        {
            const bool isq = (cg < 4);
            uint16_t* dst = isq ? ldsQ : ldsK;
            #pragma unroll
            for (int nt = 0; nt < 3; ++nt) {
                int colW = cg * 48 + nt * 16 + lr;
                int jj = isq ? colW : (colW - 192);
                #pragma unroll
                for (int mt = 0; mt < 2; ++mt) {
                    #pragma unroll
                    for (int r = 0; r < 4; ++r) {
                        int row = mp * 32 + mt * 16 + lg * 4 + r;
                        if (row < NPIX) {
                            __bf16 bv = (__bf16)acc[mt][nt][r];
                            *(__bf16*)((char*)dst +
                                ((row * ROWB + jj * 2) ^ ((row & 7) << 4))) = bv;
                        }
                    }
                }
            }
        }
        __syncthreads();   // B2: q/k visible

        // ---- Phase 4: swapped-operand GEMM2 + lane-local softmax + stores
        float* outw = out + (size_t)(wbase + j) * (NHEAD * NPIX * NPIX);
        const uint32_t qswz = (uint32_t)((qrc & 7) << 4);

        auto do_head = [&](int h) {
            const bf16x8 qfr = *(const bf16x8*)((const char*)ldsQ +
                (((uint32_t)(qrc * ROWB + h * 64 + lg * 16)) ^ qswz));

            float v[16];
            #pragma unroll
            for (int nt2 = 0; nt2 < 4; ++nt2) {
                int krow = nt2 * 16 + lr;
                if (krow > 48) krow = 48;             // clamp (masked later)
                const bf16x8 kfr = *(const bf16x8*)((const char*)ldsK +
                    (((uint32_t)(krow * ROWB + h * 64 + lg * 16)) ^ ((krow & 7) << 4)));
                f32x4 p = __builtin_amdgcn_mfma_f32_16x16x32_bf16(
                    kfr, qfr, f32x4{0.f, 0.f, 0.f, 0.f}, 0, 0, 0);
                #pragma unroll
                for (int r = 0; r < 4; ++r) {
                    int k = nt2 * 16 + lg * 4 + r;
                    v[nt2 * 4 + r] = (k < NPIX) ? p[r] : -INFINITY;
                }
            }

            float m = v[0];
            #pragma unroll
            for (int i = 1; i < 16; ++i) m = fmaxf(m, v[i]);
            m = fmaxf(m, __shfl_xor(m, 16, 64));
            m = fmaxf(m, __shfl_xor(m, 32, 64));

            float sum = 0.f;
            #pragma unroll
            for (int i = 0; i < 16; ++i) {
                v[i] = exp2f(v[i] - m);    // logits already in log2 domain
                sum += v[i];
            }
            sum += __shfl_xor(sum, 16, 64);
            sum += __shfl_xor(sum, 32, 64);
            const float inv = __fdividef(1.0f, sum);

            if (qrow < NPIX) {
                float* orow = outw + h * (NPIX * NPIX) + qrow * NPIX;
                #pragma unroll
                for (int nt2 = 0; nt2 < 3; ++nt2)
                    #pragma unroll
                    for (int r = 0; r < 4; ++r)
                        orow[nt2 * 16 + lg * 4 + r] = v[nt2 * 4 + r] * inv;
                if (lg == 0) orow[48] = v[12] * inv;
            }
        };

        do_head(h1);
        if (wave < 8) do_head(h1 + 4);   // heads 4,5

        __syncthreads();   // B3: q/k reads done before next window's staging
    }
}

extern "C" void kernel_launch(void* const* d_in, const int* in_sizes, int n_in,
                              void* d_out, int out_size, void* d_ws, size_t ws_size,
                              hipStream_t stream) {
    const float* x  = (const float*)d_in[0];
    const float* W  = (const float*)d_in[1];
    const float* bq = (const float*)d_in[2];
    float* out = (float*)d_out;
    uint16_t* wbf = (uint16_t*)d_ws;   // 147456 B swizzled W + 1536 B bias f32

    wconv_kernel<<<(384 * 192 + 255) / 256, 256, 0, stream>>>(W, bq, wbf);
    attn_win_kernel<<<NBLK, 1024, LDSSZ, stream>>>(x, wbf, out);
}

// Round 20
// 314.308 us; speedup vs baseline: 9.2764x; 1.9215x over previous
//
#include <hip/hip_runtime.h>
#include <hip/hip_bf16.h>
#include <math.h>
#include <stdint.h>

// Problem constants
#define CCH   192      // channels
#define HWD   224      // H = W = 224
#define NWIN  8192     // 8 * 32 * 32 windows
#define NPIX  49       // 7*7 pixels per window
#define KDIM  192      // GEMM1 K
#define NHEAD 6
#define ROWB  (KDIM * 2)   // 384 bytes per LDS row
#define MULQ  0.2550348616845977f   // 32^-0.5 * log2(e), folded into W_q/b_q

typedef __bf16 bf16x8 __attribute__((ext_vector_type(8)));
typedef __bf16 bf16x2 __attribute__((ext_vector_type(2)));
typedef float  f32x4  __attribute__((ext_vector_type(4)));

// Convert W (384x192 f32) to bf16 pre-swizzled into MFMA B-fragment order,
// with scale*log2e pre-folded into the q half (rows 0..191).
// out[((ng*6 + kk)*4 + lg)*128 + lr*8 + e] = W[(ng*16+lr)*192 + kk*32+lg*8+e]
// Also writes the (scaled) bias as f32 at wbf+73728.
__global__ void wconv_kernel(const float* __restrict__ w,
                             const float* __restrict__ bq,
                             uint16_t* __restrict__ wbf) {
    int o = blockIdx.x * 256 + threadIdx.x;
    if (o >= 384 * 192) return;
    if (o < 384) {
        float bb = bq[o];
        if (o < 192) bb *= MULQ;
        ((float*)(wbf + 384 * 192))[o] = bb;
    }
    int e  = o & 7;
    int t  = o >> 3;
    int lr = t & 15;  t >>= 4;
    int lg = t & 3;   t >>= 2;
    int kk = t % 6;
    int ng = t / 6;
    int col  = ng * 16 + lr;
    int kcol = kk * 32 + lg * 8 + e;
    float wv = w[col * KDIM + kcol];
    if (col < 192) wv *= MULQ;            // q half pre-scaled
    __bf16 v = (__bf16)wv;
    wbf[o] = __builtin_bit_cast(uint16_t, v);
}

// One block per window, 1024 threads = 16 waves, 2 blocks/CU (32 waves/CU).
// Final kernel (best verified: 313.5 us scored). Session findings baked in:
// - unified reg file splits ~evenly VGPR/AGPR; arch cap = wave budget / 2.
//   At (1024,8): 32 arch regs. This kernel fits exactly; ANY value held
//   live across a barrier spills (R5/R6/R9/R13/R15/R17/R19 all confirmed).
// - occupancy beyond 16 waves/CU is perf-neutral here (R4 == R10).
// - softmax is free (R14 ablation: V0 == V2); phases are additive.
// - register prefetch, global_load_lds DMA (12x FETCH on 4B scatter), and
//   multi-window LDS staging all regress — gather latency stays exposed.
__global__ __launch_bounds__(1024, 8)
void attn_win_kernel(const float* __restrict__ x,
                     const uint16_t* __restrict__ wbf,
                     float* __restrict__ out) {
    __shared__ uint16_t ldsA[NPIX * KDIM];   // xw tile, later q
    __shared__ uint16_t ldsB[NPIX * KDIM];   // k

    const int tid  = threadIdx.x;
    const int wave = tid >> 6;   // 0..15
    const int l    = tid & 63;
    const int lg   = l >> 4;     // 0..3
    const int lr   = l & 15;     // 0..15

    // XCD-bijective remap: each XCD gets one contiguous batch image (8192 % 8 == 0)
    const int win = ((blockIdx.x & 7) << 10) | (blockIdx.x >> 3);
    const int b   = win >> 10;
    const int wh  = (win >> 5) & 31;
    const int ww  = win & 31;
    const int h0 = wh * 7, w0 = ww * 7;

    const float* bias = (const float*)(wbf + 384 * 192);

    // ---- Phase 1: gather x window -> ldsA (bf16, XOR-swizzled rows).
    // lane = pixel (49 active), wave owns 12 channels. All 12 loads issued
    // before any LDS write (single exposed HBM latency; regs are phase-local).
    if (l < NPIX) {
        int r = (l * 37) >> 8;          // l / 7 for l in [0,49)
        int s = l - r * 7;
        const float* xp = x + (size_t)(b * CCH + wave * 12) * (HWD * HWD)
                            + (h0 + r) * HWD + (w0 + s);
        float g[12];
        #pragma unroll
        for (int c = 0; c < 12; ++c)
            g[c] = xp[(size_t)c * (HWD * HWD)];
        const uint32_t rb  = (uint32_t)(l * ROWB + wave * 24);
        const uint32_t swz = (uint32_t)((l & 7) << 4);
        #pragma unroll
        for (int c = 0; c < 12; c += 2) {
            bf16x2 p = { (__bf16)g[c], (__bf16)g[c + 1] };
            uint32_t byte = (rb + (uint32_t)(c * 2)) ^ swz;
            *(uint32_t*)((char*)ldsA + byte) = __builtin_bit_cast(uint32_t, p);
        }
    }
    __syncthreads();

    // ---- Phase 2: GEMM1  qk[64 x 384] = xw @ W^T (+bias via acc init)
    // wave = (mp, cg): rows mp*32..mp*32+31, cols cg*48..cg*48+47.
    const int mp = wave & 1;
    const int cg = wave >> 1;    // 0..7
    f32x4 acc[2][3];
    #pragma unroll
    for (int nt = 0; nt < 3; ++nt) {
        float bb = bias[cg * 48 + nt * 16 + lr];   // col = lr across all 4 regs
        #pragma unroll
        for (int mt = 0; mt < 2; ++mt)
            acc[mt][nt] = f32x4{bb, bb, bb, bb};
    }

    #pragma unroll
    for (int kk = 0; kk < 6; ++kk) {
        bf16x8 afr[2];
        #pragma unroll
        for (int mt = 0; mt < 2; ++mt) {
            int row = mp * 32 + mt * 16 + lr;
            if (row > 48) row = 48;                       // clamp: no pad rows
            int byte = (row * ROWB + kk * 64 + lg * 16) ^ ((row & 7) << 4);
            afr[mt] = *(const bf16x8*)((const char*)ldsA + byte);
        }
        // batch the 3 B-fragment loads (independent, issue back-to-back)
        bf16x8 bfr[3];
        #pragma unroll
        for (int nt = 0; nt < 3; ++nt)
            bfr[nt] = *(const bf16x8*)(
                wbf + (((cg * 3 + nt) * 6 + kk) * 4 + lg) * 128 + lr * 8);
        #pragma unroll
        for (int nt = 0; nt < 3; ++nt)
            #pragma unroll
            for (int mt = 0; mt < 2; ++mt)
                acc[mt][nt] = __builtin_amdgcn_mfma_f32_16x16x32_bf16(
                    afr[mt], bfr[nt], acc[mt][nt], 0, 0, 0);
    }
    __syncthreads();   // all GEMM1 reads of ldsA done before q overwrites it

    // ---- Phase 3: q -> ldsA, k -> ldsB (bf16); bias/scale already applied
    {
        const bool isq = (cg < 4);
        uint16_t* dst = isq ? ldsA : ldsB;
        #pragma unroll
        for (int nt = 0; nt < 3; ++nt) {
            int colW = cg * 48 + nt * 16 + lr;    // 0..383
            int jj = isq ? colW : (colW - 192);
            #pragma unroll
            for (int mt = 0; mt < 2; ++mt) {
                #pragma unroll
                for (int r = 0; r < 4; ++r) {
                    int row = mp * 32 + mt * 16 + lg * 4 + r;
                    if (row < NPIX) {
                        __bf16 bv = (__bf16)acc[mt][nt][r];
                        *(__bf16*)((char*)dst +
                            ((row * ROWB + jj * 2) ^ ((row & 7) << 4))) = bv;
                    }
                }
            }
        }
    }
    __syncthreads();

    // ---- Phase 4: swapped-operand GEMM2 + lane-local softmax + direct stores.
    // mfma(K_tile, Q_tile): D col = q-row, D row = k-idx. Lane (lg,lr) of wave
    // (qt = wave&3) holds S[qrow = qt*16+lr][k = nt2*16 + lg*4 + r].
    // 24 (head,qt) pairs over 16 waves: wave w does head w>>2 (0..3), and
    // waves 0-7 also do head (w>>2)+4.
    float* outw = out + (size_t)win * (NHEAD * NPIX * NPIX);
    const int qt    = wave & 3;
    const int qrow  = qt * 16 + lr;
    const int qrc   = qrow > 48 ? 48 : qrow;            // clamped read row
    const uint32_t qswz = (uint32_t)((qrc & 7) << 4);

    auto do_head = [&](int h) {
        const bf16x8 qfr = *(const bf16x8*)((const char*)ldsA +
            (((uint32_t)(qrc * ROWB + h * 64 + lg * 16)) ^ qswz));

        float v[16];
        #pragma unroll
        for (int nt2 = 0; nt2 < 4; ++nt2) {
            int krow = nt2 * 16 + lr;
            if (krow > 48) krow = 48;                   // clamp (masked later)
            const bf16x8 kfr = *(const bf16x8*)((const char*)ldsB +
                (((uint32_t)(krow * ROWB + h * 64 + lg * 16)) ^ ((krow & 7) << 4)));
            f32x4 p = __builtin_amdgcn_mfma_f32_16x16x32_bf16(
                kfr, qfr, f32x4{0.f, 0.f, 0.f, 0.f}, 0, 0, 0);
            #pragma unroll
            for (int r = 0; r < 4; ++r) {
                int k = nt2 * 16 + lg * 4 + r;
                v[nt2 * 4 + r] = (k < NPIX) ? p[r] : -INFINITY;
            }
        }

        // row softmax: 16 in-lane values + 2 cross-lane steps (l^16, l^32)
        float m = v[0];
        #pragma unroll
        for (int i = 1; i < 16; ++i) m = fmaxf(m, v[i]);
        m = fmaxf(m, __shfl_xor(m, 16, 64));
        m = fmaxf(m, __shfl_xor(m, 32, 64));

        float sum = 0.f;
        #pragma unroll
        for (int i = 0; i < 16; ++i) {
            v[i] = exp2f(v[i] - m);    // logits already in log2 domain
            sum += v[i];
        }
        sum += __shfl_xor(sum, 16, 64);
        sum += __shfl_xor(sum, 32, 64);
        const float inv = __fdividef(1.0f, sum);

        if (qrow < NPIX) {
            float* orow = outw + h * (NPIX * NPIX) + qrow * NPIX;
            #pragma unroll
            for (int nt2 = 0; nt2 < 3; ++nt2)
                #pragma unroll
                for (int r = 0; r < 4; ++r)
                    orow[nt2 * 16 + lg * 4 + r] = v[nt2 * 4 + r] * inv;
            if (lg == 0) orow[48] = v[12] * inv;
        }
    };

    const int h1 = wave >> 2;      // 0..3
    do_head(h1);
    if (wave < 8) do_head(h1 + 4); // heads 4,5
}

extern "C" void kernel_launch(void* const* d_in, const int* in_sizes, int n_in,
                              void* d_out, int out_size, void* d_ws, size_t ws_size,
                              hipStream_t stream) {
    const float* x  = (const float*)d_in[0];
    const float* W  = (const float*)d_in[1];
    const float* bq = (const float*)d_in[2];
    float* out = (float*)d_out;
    uint16_t* wbf = (uint16_t*)d_ws;   // 147456 B swizzled W + 1536 B bias f32

    wconv_kernel<<<(384 * 192 + 255) / 256, 256, 0, stream>>>(W, bq, wbf);
    attn_win_kernel<<<NWIN, 1024, 0, stream>>>(x, wbf, out);
}